// Round 6
// baseline (742.110 us; speedup 1.0000x reference)
//
#include <hip/hip_runtime.h>
#include <hip/hip_bf16.h>

typedef unsigned int u32;
typedef unsigned short u16;

#define DEVINL __device__ __forceinline__

constexpr int Nn  = 25000;
constexpr int Ee  = 100000;
constexpr int NCc = 8000;
constexpr int Aa  = 50000;
constexpr int ECc = 24000;
constexpr int TCOLS = 1088;
constexpr int WPSZ  = TCOLS*32;
constexpr int TT_ROW = 561;
constexpr int NB_N = (Nn + 255)/256;   // 98
constexpr int NB_C = (NCc + 255)/256;  // 32
constexpr int NSEGB = 3*(NB_N + NB_C); // 390 (256-wide scan blocks)
constexpr int NBLK = 512;
constexpr int LTH  = 512;
constexpr int NBAR = 12;
constexpr int GV_N = (Nn + 15)/16;   // 1563
constexpr int GV_C = (NCc + 15)/16;  // 500
constexpr int T_CNT = 2*Ee + 2*ECc + 2*Aa;           // 348000
constexpr int T_PLC = Ee + ECc + 2*Aa + 4*WPSZ;      // 363264

typedef float f32x4 __attribute__((ext_vector_type(4)));
typedef _Float16 h16x2 __attribute__((ext_vector_type(2)));
typedef _Float16 h16x8 __attribute__((ext_vector_type(8)));

DEVINL float b2f(u16 u){ union{u32 i;float f;}v; v.i = ((u32)u)<<16; return v.f; }
DEVINL float bfl(u32 u){ union{u32 i;float f;}v; v.i = u<<16; return v.f; }
DEVINL float bfh(u32 u){ union{u32 i;float f;}v; v.i = u & 0xffff0000u; return v.f; }
DEVINL u16 f2b(float f){ union{float f;u32 i;}v; v.f=f; u32 i=v.i;
  return (u16)((i + 0x7fffu + ((i>>16)&1u)) >> 16); }
DEVINL u16 f2h(float x){ union{ _Float16 h; u16 u; } v; v.h = (_Float16)x; return v.u; }
DEVINL u32 pkh2(float a, float b){
  union{ _Float16 h[2]; u32 u; } v;
  v.h[0] = (_Float16)a; v.h[1] = (_Float16)b; return v.u;
}
DEVINL float ldw(const void* p, long i, int f){
  return f ? ((const float*)p)[i] : b2f(((const u16*)p)[i]);
}
DEVINL float dot2f(u32 a, u32 b, float c){
  union U{u32 u; h16x2 h;};
  U ua; ua.u = a; U ub; ub.u = b;
#if __has_builtin(__builtin_amdgcn_fdot2)
  return __builtin_amdgcn_fdot2(ua.h, ub.h, c, false);
#else
  return c + (float)ua.h[0]*(float)ub.h[0] + (float)ua.h[1]*(float)ub.h[1];
#endif
}

struct Prm {
  const int *ei, *cei, *n2c;
  const void *ef, *cef;
  const void *nn1w,*nn1b,*cnn1w,*cnn1b,*nn2w,*nn2b,*rootw,*cnn2w,*cnn2b,*crootw;
  const void *rootb,*n2cw,*n2cb,*crootb,*c2nw,*c2nb;
  const void *x_in,*c_in; void* out;
  int *deg_nd,*deg_ce,*deg_n2c,*deg_c2n,*cnt_sn,*cnt_sc;
  int *cur_n,*cur_c,*cur_an,*cur_ac,*cur_dn,*cur_dc;
  int *offs_n,*offs_c,*offs_an,*offs_ac,*doffs_n,*doffs_c;
  int *bs0,*bs1,*bs2,*bs3,*bs4,*bs5;
  int *an2c,*ac2n;
  int2 *sdp_n,*sdp_c;
  u32 *hp_n,*hp_c;
  u16 *Wp4;
  float *dmax; int *dzc; int *flagp;
  float *frn,*frc,*msgN,*msgC,*xB,*xC,*cC0,*cC1,*mN,*mC;
  int *gc,*rc,*fl,*tk;
};

DEVINL void segof(int bid, int& seg, int& rb){
  seg = 0; rb = bid;
  while (true){
    int nb = (seg & 1) ? NB_C : NB_N;
    if (rb < nb) break;
    rb -= nb; seg++;
  }
}

// ---------- device-wide barrier: tree arrivals + per-block distributed release flags ----------
DEVINL void gbar(int* gc, int* rc, int* fl, int id){
  __shared__ int rel;
  __syncthreads();
  if (threadIdx.x == 0){
    __threadfence();
    int g = blockIdx.x & 7;
    int last = 0;
    if (atomicAdd(gc + (id*8 + g)*32, 1) == 63)
      if (atomicAdd(rc + id*32, 1) == 7) last = 1;
    rel = last;
  }
  __syncthreads();
  if (rel){
    // releaser block: 512 threads write 512 per-block flags (distinct 128B lines)
    __hip_atomic_store(fl + ((size_t)id*NBLK + threadIdx.x)*32, 1,
                       __ATOMIC_RELEASE, __HIP_MEMORY_SCOPE_AGENT);
  } else if (threadIdx.x == 0){
    int* myfl = fl + ((size_t)id*NBLK + blockIdx.x)*32;
    while (!__hip_atomic_load(myfl, __ATOMIC_RELAXED, __HIP_MEMORY_SCOPE_AGENT))
      __builtin_amdgcn_s_sleep(8);
    (void)__hip_atomic_load(myfl, __ATOMIC_ACQUIRE, __HIP_MEMORY_SCOPE_AGENT);
    __threadfence();
  }
  __syncthreads();
}

// ---------- conv tile body (r4/r5-verified) ----------
DEVINL void conv_phase(int v, const void* base, int braw,
    const float* adm, const int* sidx, const int* soffs, const int* sdeg, int M,
    const int2* sdp, const u32* hp, const int* offs, int E_,
    const u16* Wp, const void* rb, long rboff, int f,
    float* feat_root, float* msg, u32* Tt, u32* hws){
  int tid = threadIdx.x;
  int w = tid >> 6, lane = tid & 63;
  int quad = lane >> 4, lm = lane & 15;
  int n0 = v * 16;
  int n = n0 + lm;
  int nc = n < M ? n : M-1;
  long bidx = (long)nc*32 + quad*8;
  float fv[8];
  if (braw && f == 0){
    uint4 q = *(const uint4*)((const u16*)base + bidx);
    fv[0]=bfl(q.x); fv[1]=bfh(q.x); fv[2]=bfl(q.y); fv[3]=bfh(q.y);
    fv[4]=bfl(q.z); fv[5]=bfh(q.z); fv[6]=bfl(q.w); fv[7]=bfh(q.w);
  } else {
    const float4* bp = (const float4*)((const float*)base + bidx);
    float4 q0 = bp[0], q1 = bp[1];
    fv[0]=q0.x; fv[1]=q0.y; fv[2]=q0.z; fv[3]=q0.w;
    fv[4]=q1.x; fv[5]=q1.y; fv[6]=q1.z; fv[7]=q1.w;
  }
  if (adm){
    int slo = soffs[nc], scnt = sdeg[nc];
    float ac[8] = {0,0,0,0,0,0,0,0};
    for (int k = 0; k < scnt; k++){
      const float4* mp = (const float4*)(adm + (size_t)sidx[slo + k]*32 + quad*8);
      float4 a0 = mp[0], a1 = mp[1];
      ac[0]+=a0.x; ac[1]+=a0.y; ac[2]+=a0.z; ac[3]+=a0.w;
      ac[4]+=a1.x; ac[5]+=a1.y; ac[6]+=a1.z; ac[7]+=a1.w;
    }
    float inv = 1.f/(float)(scnt > 1 ? scnt : 1);
    #pragma unroll
    for (int j = 0; j < 8; j++) fv[j] += ac[j]*inv;
  }
  union { h16x8 v; u32 u[4]; } bf;
  #pragma unroll
  for (int j = 0; j < 4; j++) bf.u[j] = pkh2(fv[2*j], fv[2*j+1]);

  #define AFR(ct) (*(const h16x8*)(Wp + (size_t)((ct)*16 + lm)*32 + quad*8))
  f32x4 z4 = {0.f, 0.f, 0.f, 0.f};
  #pragma unroll
  for (int g = 0; g < 2; g++){
    int q = w + 8*g;
    f32x4 c0 = __builtin_amdgcn_mfma_f32_16x16x32_f16(AFR(4*q+0), bf.v, z4, 0, 0, 0);
    f32x4 c1 = __builtin_amdgcn_mfma_f32_16x16x32_f16(AFR(4*q+1), bf.v, z4, 0, 0, 0);
    f32x4 c2 = __builtin_amdgcn_mfma_f32_16x16x32_f16(AFR(4*q+2), bf.v, z4, 0, 0, 0);
    f32x4 c3 = __builtin_amdgcn_mfma_f32_16x16x32_f16(AFR(4*q+3), bf.v, z4, 0, 0, 0);
    int rbase = lm*TT_ROW;
    int ob = quad*4;
    #pragma unroll
    for (int i = 0; i < 4; i++){
      Tt[rbase + (ob+i)*17 + q]      = pkh2(c0[i], c2[i]);
      Tt[rbase + (16+ob+i)*17 + q]   = pkh2(c1[i], c3[i]);
    }
  }
  if (w < 4){
    int ct = 64 + w;
    f32x4 c = __builtin_amdgcn_mfma_f32_16x16x32_f16(AFR(ct), bf.v, z4, 0, 0, 0);
    if (ct < 66){
      int p0 = (ct-64)*8 + quad*2;
      Tt[lm*TT_ROW + 544 + p0]     = pkh2(c[0], c[1]);
      Tt[lm*TT_ROW + 544 + p0 + 1] = pkh2(c[2], c[3]);
    } else if (n < M){
      int o = (ct-66)*16 + quad*4;
      float4 vv = make_float4(c[0] + ldw(rb, rboff+o,   f),
                              c[1] + ldw(rb, rboff+o+1, f),
                              c[2] + ldw(rb, rboff+o+2, f),
                              c[3] + ldw(rb, rboff+o+3, f));
      *(float4*)&feat_root[(size_t)n*32 + o] = vv;
    }
  }
  __syncthreads();

  int lo = offs[n0];
  int hi = (n0 + 16 < M) ? offs[n0 + 16] : E_;
  int eg = quad, kk = lm;
  int pos = lo + w*4;
  u32 hp0 = 0, hp1 = 0; int sd0 = 0, sd1 = 0;
  { int idx = pos*16 + lane;      if (idx < hi*16) hp0 = hp[idx];
    idx = (pos+32)*16 + lane;     if (idx < hi*16) hp1 = hp[idx]; }
  if (lane < 8){
    int idx = pos*2 + lane;       if (idx < hi*2) sd0 = ((const int*)sdp)[idx];
    idx = (pos+32)*2 + lane;      if (idx < hi*2) sd1 = ((const int*)sdp)[idx];
  }
  u32* hwsw = hws + w*64;
  for (; pos < hi; pos += 32){
    int np = pos + 64;
    u32 hp2 = 0; int sd2 = 0;
    { int idx = np*16 + lane; if (idx < hi*16) hp2 = hp[idx]; }
    if (lane < 8){ int idx = np*2 + lane; if (idx < hi*2) sd2 = ((const int*)sdp)[idx]; }
    hwsw[lane] = hp0;
    int sn = __shfl(sd0, 2*eg);
    int ds = __shfl(sd0, 2*eg + 1);
    bool valid = (pos + eg < hi);
    int sr = sn - n0; sr = sr < 0 ? 0 : (sr > 15 ? 15 : sr);
    const u32* Tr = Tt + sr*TT_ROW;
    const u32* T0 = Tr + 34*kk;
    const uint4* Hp4 = (const uint4*)&hwsw[eg*16];
    union{u32 u; h16x2 h;} b2u; b2u.u = Tr[544 + kk];
    float m0 = (float)b2u.h[0], m1 = (float)b2u.h[1];
    #pragma unroll
    for (int g = 0; g < 4; g++){
      uint4 hv4 = Hp4[g];
      m0 = dot2f(hv4.x, T0[4*g+0], m0);  m1 = dot2f(hv4.x, T0[17+4*g+0], m1);
      m0 = dot2f(hv4.y, T0[4*g+1], m0);  m1 = dot2f(hv4.y, T0[17+4*g+1], m1);
      m0 = dot2f(hv4.z, T0[4*g+2], m0);  m1 = dot2f(hv4.z, T0[17+4*g+2], m1);
      m0 = dot2f(hv4.w, T0[4*g+3], m0);  m1 = dot2f(hv4.w, T0[17+4*g+3], m1);
    }
    if (valid){
      float* ap = msg + (size_t)ds*32 + 2*kk;
      ap[0] = m0;
      ap[1] = m1;
    }
    hp0 = hp1; sd0 = sd1; hp1 = hp2; sd1 = sd2;
  }
  #undef AFR
  __syncthreads();
}

// ---------- update: weight stage + per-tile body ----------
DEVINL void upd_loadw(const void* w_, long woff, const void* b_, long boff, int f, char* smem){
  float* wsm = (float*)smem;
  float* bsv = wsm + 1024;
  int tid = threadIdx.x;
  for (int idx = tid; idx < 1024; idx += LTH) wsm[idx] = ldw(w_, woff + idx, f);
  if (tid < 32) bsv[tid] = ldw(b_, boff + tid, f);
  __syncthreads();
}

DEVINL void upd_tile(int v, const float* msg, const int* doffs, const int* deg,
    const float* froot, int M, float* feat, float* mout, char* smem){
  float* wsm = (float*)smem;
  float* bsv = wsm + 1024;
  float (*rows)[33] = (float(*)[33])(bsv + 32);
  int tid = threadIdx.x;
  int nl = tid >> 5, o = tid & 31;
  int n = v*16 + nl;
  long i = (long)n*32 + o;
  if (n < M){
    int lo = doffs[n], dg = deg[n];
    float a = 0.f;
    for (int k = 0; k < dg; k++) a += msg[(size_t)(lo + k)*32 + o];
    float d = (float)(dg > 1 ? dg : 1);
    float val = fmaxf(a/d + froot[i], 0.f);
    rows[nl][o] = val;
    feat[i] = val;
  }
  __syncthreads();
  if (n < M){
    float acc = bsv[o];
    #pragma unroll
    for (int j = 0; j < 32; j++) acc += rows[nl][j]*wsm[j*32+o];
    mout[i] = acc;
  }
  __syncthreads();
}

// ---------- the whole model: preprocessing + layers + store, 12 device barriers ----------
__global__ __launch_bounds__(512, 4) void k_all(Prm p){
  __shared__ __align__(16) char smem[37952];
  __shared__ int shv;
  u32* Tt  = (u32*)smem;
  u32* hws = (u32*)(smem + 16*TT_ROW*4);
  int tid = threadIdx.x;
  int bid = blockIdx.x;

  // ---- P0: histograms (all blocks) + dtype-detect partials (blocks < 64) ----
  for (int i = bid*LTH + tid; i < T_CNT; i += NBLK*LTH){
    int t = i;
    if (t < Ee)                             atomicAdd(&p.deg_nd[p.ei[Ee + t]], 1);
    else if ((t -= Ee) < ECc)               atomicAdd(&p.deg_ce[p.cei[ECc + t]], 1);
    else if ((t -= ECc) < Aa)               atomicAdd(&p.deg_n2c[p.n2c[Aa + t]], 1);
    else if ((t -= Aa) < Aa)                atomicAdd(&p.deg_c2n[p.n2c[t]], 1);
    else if ((t -= Aa) < Ee)                atomicAdd(&p.cnt_sn[p.ei[t]], 1);
    else if ((t -= Ee) < ECc)               atomicAdd(&p.cnt_sc[p.cei[t]], 1);
  }
  if (bid < 64){
    float lm = 0.f; int lz = 0;
    for (int i = bid*LTH + tid; i < Nn*32; i += 64*LTH){
      u16 v = ((const u16*)p.x_in)[i];
      if (v == 0) lz++;
      lm = fmaxf(lm, fabsf(b2f(v)));
    }
    #pragma unroll
    for (int off = 32; off; off >>= 1){
      lm = fmaxf(lm, __shfl_down(lm, off));
      lz += __shfl_down(lz, off);
    }
    __shared__ float smax[8]; __shared__ int szc[8];
    if ((tid & 63) == 0){ smax[tid >> 6] = lm; szc[tid >> 6] = lz; }
    __syncthreads();
    if (tid == 0){
      float m = 0.f; int z = 0;
      #pragma unroll
      for (int q = 0; q < 8; q++){ m = fmaxf(m, smax[q]); z += szc[q]; }
      p.dmax[bid*32] = m;
      p.dzc[bid*32]  = z;
    }
  }
  gbar(p.gc, p.rc, p.fl, 0);

  // ---- P1: flag compute (block 511) + 6-segment scan local pass (dual-256 halves) ----
  if (bid == 511 && tid == 0){
    float m = 0.f; int z = 0;
    for (int k = 0; k < 64; k++){ m = fmaxf(m, p.dmax[k*32]); z += p.dzc[k*32]; }
    *p.flagp = (m > 1e6f || z > (Nn*32)/4) ? 1 : 0;
  }
  if (bid < (NSEGB+1)/2){
    int* s = (int*)smem;
    int t = tid & 255, h = tid >> 8;
    int origb = bid*2 + h;
    bool active = origb < NSEGB;
    int seg = 0, rb = 0;
    if (active) segof(origb, seg, rb);
    const int* cnt; int* offs; int* bs; int M;
    switch (seg){
      case 0: cnt=p.cnt_sn;  offs=p.offs_n;  bs=p.bs0; M=Nn;  break;
      case 1: cnt=p.cnt_sc;  offs=p.offs_c;  bs=p.bs1; M=NCc; break;
      case 2: cnt=p.deg_c2n; offs=p.offs_an; bs=p.bs2; M=Nn;  break;
      case 3: cnt=p.deg_n2c; offs=p.offs_ac; bs=p.bs3; M=NCc; break;
      case 4: cnt=p.deg_nd;  offs=p.doffs_n; bs=p.bs4; M=Nn;  break;
      default:cnt=p.deg_ce;  offs=p.doffs_c; bs=p.bs5; M=NCc; break;
    }
    int idx = rb*256 + t;
    int val = (active && idx < M) ? cnt[idx] : 0;
    s[tid] = val; __syncthreads();
    for (int d = 1; d < 256; d <<= 1){
      int tv = (t >= d) ? s[tid-d] : 0;
      __syncthreads();
      s[tid] += tv;
      __syncthreads();
    }
    if (active && idx < M) offs[idx] = s[tid] - val;
    if (active && t == 255) bs[rb] = s[tid];
  }
  gbar(p.gc, p.rc, p.fl, 1);

  // ---- P2: scan fix pass (redundant spine reduce, dual halves) ----
  if (bid < (NSEGB+1)/2){
    int* s = (int*)smem;
    int t = tid & 255, h = tid >> 8;
    int origb = bid*2 + h;
    bool active = origb < NSEGB;
    int seg = 0, rb = 0;
    if (active) segof(origb, seg, rb);
    int* offs; const int* bsp; int M;
    switch (seg){
      case 0: offs=p.offs_n;  bsp=p.bs0; M=Nn;  break;
      case 1: offs=p.offs_c;  bsp=p.bs1; M=NCc; break;
      case 2: offs=p.offs_an; bsp=p.bs2; M=Nn;  break;
      case 3: offs=p.offs_ac; bsp=p.bs3; M=NCc; break;
      case 4: offs=p.doffs_n; bsp=p.bs4; M=Nn;  break;
      default:offs=p.doffs_c; bsp=p.bs5; M=NCc; break;
    }
    int val = (active && t < rb) ? bsp[t] : 0;
    s[tid] = val; __syncthreads();
    #pragma unroll
    for (int d = 128; d; d >>= 1){
      if (t < d) s[tid] += s[tid + d];
      __syncthreads();
    }
    int prefix = s[h*256];
    int idx = rb*256 + t;
    if (active && idx < M) offs[idx] += prefix;
  }
  gbar(p.gc, p.rc, p.fl, 2);

  int f = *p.flagp;   // written P1, published via barrier chain

  // ---- P3: place (src+dst slots) + h-pack + assignment CSRs + weight pack ----
  {
    float* w1n = (float*)smem;          // 512 (2 layers x 256)
    float* w1c = w1n + 512;             // 512
    float* b1n = w1c + 512;             // 64
    float* b1c = b1n + 64;              // 64
    w1n[tid] = ldw(p.nn1w, tid, f);
    w1c[tid] = ldw(p.cnn1w, tid, f);
    if (tid < 64){ b1n[tid] = ldw(p.nn1b, tid, f); b1c[tid] = ldw(p.cnn1b, tid, f); }
    __syncthreads();
    for (int i = bid*LTH + tid; i < T_PLC; i += NBLK*LTH){
      if (i < Ee + ECc){
        int isC = i >= Ee;
        int e = isC ? i - Ee : i;
        int E = isC ? ECc : Ee;
        const int* EI = isC ? p.cei : p.ei;
        int s_ = EI[e], d_ = EI[E + e];
        const int* offs = isC ? p.offs_c : p.offs_n;
        int* cur = isC ? p.cur_c : p.cur_n;
        int pp = offs[s_] + atomicAdd(&cur[s_], 1);
        const int* dofs = isC ? p.doffs_c : p.doffs_n;
        int* curd = isC ? p.cur_dc : p.cur_dn;
        int dsl = dofs[d_] + atomicAdd(&curd[d_], 1);
        (isC ? p.sdp_c : p.sdp_n)[pp] = make_int2(s_, dsl);
        const void* EF = isC ? p.cef : p.ef;
        float ev[8];
        #pragma unroll
        for (int j = 0; j < 8; j++) ev[j] = ldw(EF, (long)e*8 + j, f);
        const float* w1 = isC ? w1c : w1n;
        const float* b1 = isC ? b1c : b1n;
        u32* hp = isC ? p.hp_c : p.hp_n;
        #pragma unroll
        for (int l = 0; l < 2; l++){
          u32* hq = hp + (size_t)l*E*16 + (size_t)pp*16;
          #pragma unroll
          for (int kk = 0; kk < 16; kk++){
            float a0 = b1[l*32 + 2*kk], a1 = b1[l*32 + 2*kk+1];
            #pragma unroll
            for (int j = 0; j < 8; j++){
              a0 += ev[j]*w1[l*256 + j*32 + 2*kk];
              a1 += ev[j]*w1[l*256 + j*32 + 2*kk + 1];
            }
            hq[kk] = pkh2(fmaxf(a0, 0.f), fmaxf(a1, 0.f));
          }
        }
      } else if (i < Ee + ECc + 2*Aa){
        int t = i - Ee - ECc;
        if (t < Aa){
          int c = p.n2c[Aa + t];
          p.an2c[p.offs_ac[c] + atomicAdd(&p.cur_ac[c], 1)] = p.n2c[t];
        } else {
          t -= Aa;
          int nd = p.n2c[t];
          p.ac2n[p.offs_an[nd] + atomicAdd(&p.cur_an[nd], 1)] = p.n2c[Aa + t];
        }
      } else {
        int q = i - Ee - ECc - 2*Aa;
        int set = q / WPSZ, j = q - set*WPSZ;
        int l = set >> 1, isC = set & 1;
        const void* W2 = isC ? p.cnn2w : p.nn2w;
        const void* B2 = isC ? p.cnn2b : p.nn2b;
        const void* RW = isC ? p.crootw : p.rootw;
        int col = j >> 5, ii = j & 31;
        float v;
        if (col < 1024)      v = ldw(W2, (long)l*32768 + ((col>>5)<<10) + (ii<<5) + (col&31), f);
        else if (col < 1056) v = ldw(B2, (long)l*1024 + (ii<<5) + (col-1024), f);
        else                 v = ldw(RW, (long)l*1024 + (ii<<5) + (col-1056), f);
        p.Wp4[q] = f2h(v);
      }
    }
  }
  gbar(p.gc, p.rc, p.fl, 3);

  // ---- P4: L0 node conv (work-stealing, chunk 2, ticket 0) ----
  for (;;){
    if (tid == 0) shv = atomicAdd(&p.tk[0*32], 2);
    __syncthreads();
    int v0 = shv;
    __syncthreads();
    if (v0 >= GV_N) break;
    for (int u = 0; u < 2; u++){
      int v = v0 + u;
      if (v < GV_N)
        conv_phase(v, p.x_in, 1, nullptr, nullptr, nullptr, nullptr, Nn,
                   p.sdp_n, p.hp_n, p.offs_n, Ee, p.Wp4, p.rootb, 0, f, p.frn, p.msgN, Tt, hws);
    }
  }
  gbar(p.gc, p.rc, p.fl, 4);

  // ---- P5: L0 node update (stealing, chunk 4, ticket 1) ----
  upd_loadw(p.n2cw, 0, p.n2cb, 0, f, smem);
  for (;;){
    if (tid == 0) shv = atomicAdd(&p.tk[1*32], 4);
    __syncthreads();
    int v0 = shv;
    __syncthreads();
    if (v0 >= GV_N) break;
    for (int u = 0; u < 4; u++){
      int v = v0 + u;
      if (v < GV_N) upd_tile(v, p.msgN, p.doffs_n, p.deg_nd, p.frn, Nn, p.xB, p.mN, smem);
    }
  }
  gbar(p.gc, p.rc, p.fl, 5);

  // ---- P6: L0 clique conv (static, 500 tiles) ----
  if (bid < GV_C)
    conv_phase(bid, p.c_in, 1, p.mN, p.an2c, p.offs_ac, p.deg_n2c, NCc,
               p.sdp_c, p.hp_c, p.offs_c, ECc, p.Wp4 + 1*WPSZ, p.crootb, 0, f, p.frc, p.msgC, Tt, hws);
  gbar(p.gc, p.rc, p.fl, 6);

  // ---- P7: L0 clique update (static) ----
  upd_loadw(p.c2nw, 0, p.c2nb, 0, f, smem);
  if (bid < GV_C)
    upd_tile(bid, p.msgC, p.doffs_c, p.deg_ce, p.frc, NCc, p.cC0, p.mC, smem);
  gbar(p.gc, p.rc, p.fl, 7);

  // ---- P8: L1 node conv (stealing, ticket 2) ----
  for (;;){
    if (tid == 0) shv = atomicAdd(&p.tk[2*32], 2);
    __syncthreads();
    int v0 = shv;
    __syncthreads();
    if (v0 >= GV_N) break;
    for (int u = 0; u < 2; u++){
      int v = v0 + u;
      if (v < GV_N)
        conv_phase(v, p.xB, 0, p.mC, p.ac2n, p.offs_an, p.deg_c2n, Nn,
                   p.sdp_n, p.hp_n + (size_t)Ee*16, p.offs_n, Ee,
                   p.Wp4 + 2*WPSZ, p.rootb, 32, f, p.frn, p.msgN, Tt, hws);
    }
  }
  gbar(p.gc, p.rc, p.fl, 8);

  // ---- P9: L1 node update (stealing, ticket 3) ----
  upd_loadw(p.n2cw, 1024, p.n2cb, 32, f, smem);
  for (;;){
    if (tid == 0) shv = atomicAdd(&p.tk[3*32], 4);
    __syncthreads();
    int v0 = shv;
    __syncthreads();
    if (v0 >= GV_N) break;
    for (int u = 0; u < 4; u++){
      int v = v0 + u;
      if (v < GV_N) upd_tile(v, p.msgN, p.doffs_n, p.deg_nd, p.frn, Nn, p.xC, p.mN, smem);
    }
  }
  gbar(p.gc, p.rc, p.fl, 9);

  // ---- P10: L1 clique conv (static) ----
  if (bid < GV_C)
    conv_phase(bid, p.cC0, 0, p.mN, p.an2c, p.offs_ac, p.deg_n2c, NCc,
               p.sdp_c, p.hp_c + (size_t)ECc*16, p.offs_c, ECc,
               p.Wp4 + 3*WPSZ, p.crootb, 32, f, p.frc, p.msgC, Tt, hws);
  gbar(p.gc, p.rc, p.fl, 10);

  // ---- P11: L1 clique update (static) ----
  upd_loadw(p.c2nw, 1024, p.c2nb, 32, f, smem);
  if (bid < GV_C)
    upd_tile(bid, p.msgC, p.doffs_c, p.deg_ce, p.frc, NCc, p.cC1, p.mC, smem);
  gbar(p.gc, p.rc, p.fl, 11);

  // ---- P12: store ----
  int tot = Nn*32 + NCc*32;
  for (int i = bid*LTH + tid; i < tot; i += NBLK*LTH){
    float v;
    if (i < Nn*32){
      int n = i >> 5, o = i & 31;
      int lo = p.offs_an[n], dg = p.deg_c2n[n];
      float a = 0.f;
      for (int k = 0; k < dg; k++) a += p.mC[(size_t)p.ac2n[lo + k]*32 + o];
      v = p.xC[i] + a/(float)(dg > 1 ? dg : 1);
    } else v = p.cC1[i - Nn*32];
    if (f) ((float*)p.out)[i] = v;
    else   ((u16*)p.out)[i]   = f2b(v);
  }
}

extern "C" void kernel_launch(void* const* d_in, const int* in_sizes, int n_in,
                              void* d_out, int out_size, void* d_ws, size_t ws_size,
                              hipStream_t stream){
  char* ws = (char*)d_ws;
  size_t off = 0;
  auto alloc = [&](size_t bytes){ void* p = ws + off; off += (bytes + 255) & ~(size_t)255; return p; };

  Prm p;
  p.ei  = (const int*)d_in[1];
  p.n2c = (const int*)d_in[4];
  p.cei = (const int*)d_in[5];
  p.ef  = d_in[2]; p.cef = d_in[6];
  p.nn1w = d_in[7];  p.nn1b = d_in[8];  p.nn2w = d_in[9];   p.nn2b = d_in[10];
  p.rootw = d_in[11]; p.rootb = d_in[12]; p.n2cw = d_in[13]; p.n2cb = d_in[14];
  p.cnn1w = d_in[15]; p.cnn1b = d_in[16]; p.cnn2w = d_in[17]; p.cnn2b = d_in[18];
  p.crootw = d_in[19]; p.crootb = d_in[20]; p.c2nw = d_in[21]; p.c2nb = d_in[22];
  p.x_in = d_in[0]; p.c_in = d_in[3]; p.out = d_out;

  // ---- zeroed region ----
  size_t zstart = off;
  p.deg_nd  = (int*)alloc((size_t)Nn*4);
  p.deg_ce  = (int*)alloc((size_t)NCc*4);
  p.deg_n2c = (int*)alloc((size_t)NCc*4);
  p.deg_c2n = (int*)alloc((size_t)Nn*4);
  p.cnt_sn  = (int*)alloc((size_t)Nn*4);
  p.cnt_sc  = (int*)alloc((size_t)NCc*4);
  p.cur_n   = (int*)alloc((size_t)Nn*4);
  p.cur_c   = (int*)alloc((size_t)NCc*4);
  p.cur_an  = (int*)alloc((size_t)Nn*4);
  p.cur_ac  = (int*)alloc((size_t)NCc*4);
  p.cur_dn  = (int*)alloc((size_t)Nn*4);
  p.cur_dc  = (int*)alloc((size_t)NCc*4);
  p.gc = (int*)alloc((size_t)NBAR*8*32*4);
  p.rc = (int*)alloc((size_t)NBAR*32*4);
  p.fl = (int*)alloc((size_t)NBAR*NBLK*32*4);
  p.tk = (int*)alloc((size_t)4*32*4);
  size_t zbytes = off - zstart;

  // ---- non-zeroed ----
  p.dmax = (float*)alloc((size_t)64*32*4);
  p.dzc  = (int*)alloc((size_t)64*32*4);
  p.flagp = (int*)alloc(256);
  p.xB  = (float*)alloc((size_t)Nn*32*4);
  p.xC  = (float*)alloc((size_t)Nn*32*4);
  p.cC0 = (float*)alloc((size_t)NCc*32*4);
  p.cC1 = (float*)alloc((size_t)NCc*32*4);
  p.frn = (float*)alloc((size_t)Nn*32*4);
  p.frc = (float*)alloc((size_t)NCc*32*4);
  p.msgN = (float*)alloc((size_t)Ee*32*4);
  p.msgC = (float*)alloc((size_t)ECc*32*4);
  p.mN  = (float*)alloc((size_t)Nn*32*4);
  p.mC  = (float*)alloc((size_t)NCc*32*4);
  p.offs_n  = (int*)alloc((size_t)Nn*4);
  p.offs_c  = (int*)alloc((size_t)NCc*4);
  p.offs_an = (int*)alloc((size_t)Nn*4);
  p.offs_ac = (int*)alloc((size_t)NCc*4);
  p.doffs_n = (int*)alloc((size_t)Nn*4);
  p.doffs_c = (int*)alloc((size_t)NCc*4);
  p.bs0 = (int*)alloc(512); p.bs1 = (int*)alloc(512);
  p.bs2 = (int*)alloc(512); p.bs3 = (int*)alloc(512);
  p.bs4 = (int*)alloc(512); p.bs5 = (int*)alloc(512);
  p.an2c = (int*)alloc((size_t)Aa*4);
  p.ac2n = (int*)alloc((size_t)Aa*4);
  p.sdp_n = (int2*)alloc((size_t)Ee*8);
  p.sdp_c = (int2*)alloc((size_t)ECc*8);
  p.Wp4 = (u16*)alloc((size_t)4*WPSZ*2);
  p.hp_n = (u32*)alloc((size_t)2*Ee*16*4);
  p.hp_c = (u32*)alloc((size_t)2*ECc*16*4);

  // 1. zero counters + barrier state (~1.5 MB)
  hipMemsetAsync(ws + zstart, 0, zbytes, stream);
  // 2. everything else in one persistent kernel
  k_all<<<NBLK, LTH, 0, stream>>>(p);
}

// Round 7
// 291.774 us; speedup vs baseline: 2.5434x; 2.5434x over previous
//
#include <hip/hip_runtime.h>
#include <hip/hip_bf16.h>

typedef unsigned int u32;
typedef unsigned short u16;

#define DEVINL __device__ __forceinline__

constexpr int Nn  = 25000;
constexpr int Ee  = 100000;
constexpr int NCc = 8000;
constexpr int Aa  = 50000;
constexpr int ECc = 24000;
constexpr int TCOLS = 1088;     // 34 k-rows * 32 o-cols
constexpr int WPSZ  = TCOLS*32; // one packed weight set
constexpr int TT_ROW = 561;     // u32 per T row
constexpr int NB_N = (Nn + 255)/256;   // 98
constexpr int NB_C = (NCc + 255)/256;  // 32
constexpr int NSEGB = 3*(NB_N + NB_C); // 390
// k_place_pack block ranges
constexpr int PB_EN = (Ee + 255)/256;
constexpr int PB_EC = (ECc + 255)/256;
constexpr int PB_AS = (2*Aa + 255)/256;
constexpr int PB_WP = (4*WPSZ + 255)/256;

typedef float f32x4 __attribute__((ext_vector_type(4)));
typedef _Float16 h16x2 __attribute__((ext_vector_type(2)));
typedef _Float16 h16x8 __attribute__((ext_vector_type(8)));

DEVINL float b2f(u16 u){ union{u32 i;float f;}v; v.i = ((u32)u)<<16; return v.f; }
DEVINL float bfl(u32 u){ union{u32 i;float f;}v; v.i = u<<16; return v.f; }
DEVINL float bfh(u32 u){ union{u32 i;float f;}v; v.i = u & 0xffff0000u; return v.f; }
DEVINL u16 f2b(float f){ union{float f;u32 i;}v; v.f=f; u32 i=v.i;
  return (u16)((i + 0x7fffu + ((i>>16)&1u)) >> 16); }
DEVINL u16 f2h(float x){ union{ _Float16 h; u16 u; } v; v.h = (_Float16)x; return v.u; }
DEVINL u32 pkh2(float a, float b){
  union{ _Float16 h[2]; u32 u; } v;
  v.h[0] = (_Float16)a; v.h[1] = (_Float16)b; return v.u;
}
DEVINL float ldw(const void* p, long i, int f){
  return f ? ((const float*)p)[i] : b2f(((const u16*)p)[i]);
}
DEVINL float dot2f(u32 a, u32 b, float c){
  union U{u32 u; h16x2 h;};
  U ua; ua.u = a; U ub; ub.u = b;
#if __has_builtin(__builtin_amdgcn_fdot2)
  return __builtin_amdgcn_fdot2(ua.h, ub.h, c, false);
#else
  return c + (float)ua.h[0]*(float)ub.h[0] + (float)ua.h[1]*(float)ub.h[1];
#endif
}

// ---------- fused: all histograms (full grid) + dtype detect (first 256 blocks) ----------
__global__ __launch_bounds__(256) void k_detect_count(const u16* __restrict__ p, int n,
                        u32* __restrict__ maxbits, int* __restrict__ zcnt,
                        int* __restrict__ done, int* __restrict__ flag,
                        const int* __restrict__ ei, const int* __restrict__ cei,
                        const int* __restrict__ n2c,
                        int* __restrict__ deg_nd, int* __restrict__ deg_ce,
                        int* __restrict__ deg_n2c, int* __restrict__ deg_c2n,
                        int* __restrict__ cnt_sn, int* __restrict__ cnt_sc){
  int i0 = blockIdx.x*256 + threadIdx.x;
  { int t = i0;
    if (t < Ee)                             atomicAdd(&deg_nd[ei[Ee + t]], 1);
    else if ((t -= Ee) < ECc)               atomicAdd(&deg_ce[cei[ECc + t]], 1);
    else if ((t -= ECc) < Aa)               atomicAdd(&deg_n2c[n2c[Aa + t]], 1);
    else if ((t -= Aa) < Aa)                atomicAdd(&deg_c2n[n2c[t]], 1);
    else if ((t -= Aa) < Ee)                atomicAdd(&cnt_sn[ei[t]], 1);
    else if ((t -= Ee) < ECc)               atomicAdd(&cnt_sc[cei[t]], 1);
  }
  if (blockIdx.x >= 256) return;
  float lm = 0.f; int lz = 0;
  for (int i = i0; i < n; i += 256*256){
    u16 v = p[i];
    if (v == 0) lz++;
    lm = fmaxf(lm, fabsf(b2f(v)));
  }
  #pragma unroll
  for (int off = 32; off; off >>= 1){
    lm = fmaxf(lm, __shfl_down(lm, off));
    lz += __shfl_down(lz, off);
  }
  __shared__ float smax[4]; __shared__ int szc[4];
  if ((threadIdx.x & 63) == 0){
    smax[threadIdx.x >> 6] = lm;
    szc[threadIdx.x >> 6] = lz;
  }
  __syncthreads();
  if (threadIdx.x == 0){
    float m = fmaxf(fmaxf(smax[0], smax[1]), fmaxf(smax[2], smax[3]));
    int z = szc[0] + szc[1] + szc[2] + szc[3];
    atomicMax(maxbits, __float_as_uint(m));
    atomicAdd(zcnt, z);
    __threadfence();
    if (atomicAdd(done, 1) == 255){
      float mm = __uint_as_float(*maxbits);
      *flag = (mm > 1e6f || *zcnt > n/4) ? 1 : 0;
    }
  }
}

// ---------- single-pass 6-segment scan: each block redundantly sums its prefix (L2-resident) ----------
DEVINL void segof(int bid, int& seg, int& rb){
  seg = 0; rb = bid;
  while (true){
    int nb = (seg & 1) ? NB_C : NB_N;
    if (rb < nb) break;
    rb -= nb; seg++;
  }
}

__global__ __launch_bounds__(256) void k_scan1(
    const int* __restrict__ c0, const int* __restrict__ c1,
    const int* __restrict__ c2, const int* __restrict__ c3,
    const int* __restrict__ c4, const int* __restrict__ c5,
    int* __restrict__ o0, int* __restrict__ o1, int* __restrict__ o2,
    int* __restrict__ o3, int* __restrict__ o4, int* __restrict__ o5){
  __shared__ int s[256];
  __shared__ int red[256];
  int seg, rb; segof(blockIdx.x, seg, rb);
  const int* cnt; int* offs;
  switch (seg){
    case 0: cnt=c0; offs=o0; break;
    case 1: cnt=c1; offs=o1; break;
    case 2: cnt=c2; offs=o2; break;
    case 3: cnt=c3; offs=o3; break;
    case 4: cnt=c4; offs=o4; break;
    default: cnt=c5; offs=o5; break;
  }
  int M = (seg & 1) ? NCc : Nn;
  int t = threadIdx.x;
  // prefix over [0, rb*256): all preceding indices are < M (last partial chunk is the final one)
  int part = 0;
  for (int j = t; j < rb*256; j += 256) part += cnt[j];
  red[t] = part; __syncthreads();
  #pragma unroll
  for (int d = 128; d; d >>= 1){
    if (t < d) red[t] += red[t + d];
    __syncthreads();
  }
  int prefix = red[0];
  // local inclusive scan of this chunk
  int i = rb*256 + t;
  int v = (i < M) ? cnt[i] : 0;
  s[t] = v; __syncthreads();
  for (int d = 1; d < 256; d <<= 1){
    int tv = (t >= d) ? s[t-d] : 0;
    __syncthreads();
    s[t] += tv;
    __syncthreads();
  }
  if (i < M) offs[i] = prefix + s[t] - v;
}

// ---------- fused: place (src+dst slots) + payload pack + weight pack ----------
__global__ __launch_bounds__(256) void k_place_pack(
    const int* __restrict__ ei, const int* __restrict__ cei, const int* __restrict__ n2c,
    const void* __restrict__ ef, const void* __restrict__ cef,
    const void* __restrict__ nn1w, const void* __restrict__ nn1b,
    const void* __restrict__ cnn1w, const void* __restrict__ cnn1b,
    const void* __restrict__ nn2w, const void* __restrict__ nn2b, const void* __restrict__ rootw,
    const void* __restrict__ cnn2w, const void* __restrict__ cnn2b, const void* __restrict__ crootw,
    const int* __restrict__ offs_n, const int* __restrict__ offs_c,
    const int* __restrict__ offs_an, const int* __restrict__ offs_ac,
    const int* __restrict__ doffs_n, const int* __restrict__ doffs_c,
    int* __restrict__ cur_n, int* __restrict__ cur_c,
    int* __restrict__ cur_an, int* __restrict__ cur_ac,
    int* __restrict__ cur_dn, int* __restrict__ cur_dc,
    int2* __restrict__ sdp_n, int2* __restrict__ sdp_c,
    u32* __restrict__ hp_n, u32* __restrict__ hp_c,
    int* __restrict__ an2c, int* __restrict__ ac2n,
    const int* __restrict__ flag, u16* __restrict__ Wp4){
  int b = blockIdx.x, tid = threadIdx.x;
  int f = *flag;
  if (b < PB_EN + PB_EC){
    __shared__ float w1s[2][256], b1s[2][32];
    int isC = (b >= PB_EN);
    int e = (isC ? b - PB_EN : b)*256 + tid;
    int E = isC ? ECc : Ee;
    const void* W1 = isC ? cnn1w : nn1w;
    const void* B1 = isC ? cnn1b : nn1b;
    w1s[0][tid] = ldw(W1, tid, f);
    w1s[1][tid] = ldw(W1, 256 + tid, f);
    if (tid < 32){ b1s[0][tid] = ldw(B1, tid, f); b1s[1][tid] = ldw(B1, 32 + tid, f); }
    __syncthreads();
    if (e < E){
      const int* EI = isC ? cei : ei;
      int s = EI[e], d = EI[E + e];
      int* cur = isC ? cur_c : cur_n;
      const int* offs = isC ? offs_c : offs_n;
      int p = offs[s] + atomicAdd(&cur[s], 1);
      const int* dofs = isC ? doffs_c : doffs_n;
      int* curd = isC ? cur_dc : cur_dn;
      int dsl = dofs[d] + atomicAdd(&curd[d], 1);
      (isC ? sdp_c : sdp_n)[p] = make_int2(s, dsl);
      const void* EF = isC ? cef : ef;
      float ev[8];
      #pragma unroll
      for (int j = 0; j < 8; j++) ev[j] = ldw(EF, (long)e*8 + j, f);
      u32* hp = isC ? hp_c : hp_n;
      #pragma unroll
      for (int l = 0; l < 2; l++){
        u32* hq = hp + (size_t)l*E*16 + (size_t)p*16;
        #pragma unroll
        for (int kk = 0; kk < 16; kk++){
          float a0 = b1s[l][2*kk], a1 = b1s[l][2*kk+1];
          #pragma unroll
          for (int j = 0; j < 8; j++){
            a0 += ev[j]*w1s[l][j*32 + 2*kk];
            a1 += ev[j]*w1s[l][j*32 + 2*kk + 1];
          }
          hq[kk] = pkh2(fmaxf(a0, 0.f), fmaxf(a1, 0.f));
        }
      }
    }
  } else if (b < PB_EN + PB_EC + PB_AS){
    int i = (b - PB_EN - PB_EC)*256 + tid;
    if (i < Aa){
      int c = n2c[Aa + i];
      an2c[offs_ac[c] + atomicAdd(&cur_ac[c], 1)] = n2c[i];
    } else if ((i -= Aa) < Aa){
      int nd = n2c[i];
      ac2n[offs_an[nd] + atomicAdd(&cur_an[nd], 1)] = n2c[Aa + i];
    }
  } else {
    int i = (b - PB_EN - PB_EC - PB_AS)*256 + tid;
    if (i >= 4*WPSZ) return;
    int set = i / WPSZ, j = i - set*WPSZ;
    int l = set >> 1, isC = set & 1;
    const void* W2 = isC ? cnn2w : nn2w;
    const void* B2 = isC ? cnn2b : nn2b;
    const void* RW = isC ? crootw : rootw;
    int col = j >> 5, ii = j & 31;
    float v;
    if (col < 1024)      v = ldw(W2, (long)l*32768 + ((col>>5)<<10) + (ii<<5) + (col&31), f);
    else if (col < 1056) v = ldw(B2, (long)l*1024 + (ii<<5) + (col-1024), f);
    else                 v = ldw(RW, (long)l*1024 + (ii<<5) + (col-1056), f);
    Wp4[i] = f2h(v);
  }
}

// ---------- fused conv: f16 MFMA T + dot2 streaming edges; f16-packed msg slot-store ----------
__global__ __launch_bounds__(512) void k_conv_fused(const void* __restrict__ base, int braw,
                           const float* __restrict__ adm, const int* __restrict__ sidx,
                           const int* __restrict__ soffs, const int* __restrict__ sdeg, int M,
                           const int2* __restrict__ sdp, const u32* __restrict__ hp,
                           const int* __restrict__ offs, int E_,
                           const u16* __restrict__ Wp,
                           const void* __restrict__ rb, long rboff,
                           const int* __restrict__ flag,
                           float* __restrict__ feat_root, u32* __restrict__ msgp){
  __shared__ __align__(16) u32 Tt[16*TT_ROW];
  __shared__ __align__(16) u32 hws[8][64];
  int tid = threadIdx.x;
  int w = tid >> 6, lane = tid & 63;
  int quad = lane >> 4, lm = lane & 15;
  int n0 = blockIdx.x * 16;
  int f = *flag;
  int n = n0 + lm;
  int nc = n < M ? n : M-1;
  long bidx = (long)nc*32 + quad*8;
  float fv[8];
  if (braw && f == 0){
    uint4 q = *(const uint4*)((const u16*)base + bidx);
    fv[0]=bfl(q.x); fv[1]=bfh(q.x); fv[2]=bfl(q.y); fv[3]=bfh(q.y);
    fv[4]=bfl(q.z); fv[5]=bfh(q.z); fv[6]=bfl(q.w); fv[7]=bfh(q.w);
  } else {
    const float4* bp = (const float4*)((const float*)base + bidx);
    float4 q0 = bp[0], q1 = bp[1];
    fv[0]=q0.x; fv[1]=q0.y; fv[2]=q0.z; fv[3]=q0.w;
    fv[4]=q1.x; fv[5]=q1.y; fv[6]=q1.z; fv[7]=q1.w;
  }
  if (adm){
    int slo = soffs[nc], scnt = sdeg[nc];
    float ac[8] = {0,0,0,0,0,0,0,0};
    for (int k = 0; k < scnt; k++){
      const float4* mp = (const float4*)(adm + (size_t)sidx[slo + k]*32 + quad*8);
      float4 a0 = mp[0], a1 = mp[1];
      ac[0]+=a0.x; ac[1]+=a0.y; ac[2]+=a0.z; ac[3]+=a0.w;
      ac[4]+=a1.x; ac[5]+=a1.y; ac[6]+=a1.z; ac[7]+=a1.w;
    }
    float inv = 1.f/(float)(scnt > 1 ? scnt : 1);
    #pragma unroll
    for (int j = 0; j < 8; j++) fv[j] += ac[j]*inv;
  }
  union { h16x8 v; u32 u[4]; } bf;
  #pragma unroll
  for (int j = 0; j < 4; j++) bf.u[j] = pkh2(fv[2*j], fv[2*j+1]);

  #define AFR(ct) (*(const h16x8*)(Wp + (size_t)((ct)*16 + lm)*32 + quad*8))
  f32x4 z4 = {0.f, 0.f, 0.f, 0.f};
  #pragma unroll
  for (int g = 0; g < 2; g++){
    int q = w + 8*g;
    f32x4 c0 = __builtin_amdgcn_mfma_f32_16x16x32_f16(AFR(4*q+0), bf.v, z4, 0, 0, 0);
    f32x4 c1 = __builtin_amdgcn_mfma_f32_16x16x32_f16(AFR(4*q+1), bf.v, z4, 0, 0, 0);
    f32x4 c2 = __builtin_amdgcn_mfma_f32_16x16x32_f16(AFR(4*q+2), bf.v, z4, 0, 0, 0);
    f32x4 c3 = __builtin_amdgcn_mfma_f32_16x16x32_f16(AFR(4*q+3), bf.v, z4, 0, 0, 0);
    int rbase = lm*TT_ROW;
    int ob = quad*4;
    #pragma unroll
    for (int i = 0; i < 4; i++){
      Tt[rbase + (ob+i)*17 + q]      = pkh2(c0[i], c2[i]);
      Tt[rbase + (16+ob+i)*17 + q]   = pkh2(c1[i], c3[i]);
    }
  }
  if (w < 4){
    int ct = 64 + w;
    f32x4 c = __builtin_amdgcn_mfma_f32_16x16x32_f16(AFR(ct), bf.v, z4, 0, 0, 0);
    if (ct < 66){
      int p0 = (ct-64)*8 + quad*2;
      Tt[lm*TT_ROW + 544 + p0]     = pkh2(c[0], c[1]);
      Tt[lm*TT_ROW + 544 + p0 + 1] = pkh2(c[2], c[3]);
    } else if (n < M){
      int o = (ct-66)*16 + quad*4;
      float4 v = make_float4(c[0] + ldw(rb, rboff+o,   f),
                             c[1] + ldw(rb, rboff+o+1, f),
                             c[2] + ldw(rb, rboff+o+2, f),
                             c[3] + ldw(rb, rboff+o+3, f));
      *(float4*)&feat_root[(size_t)n*32 + o] = v;
    }
  }
  __syncthreads();

  int lo = offs[n0];
  int hi = (n0 + 16 < M) ? offs[n0 + 16] : E_;
  int eg = quad, kk = lm;
  int pos = lo + w*4;
  u32 hp0 = 0, hp1 = 0; int sd0 = 0, sd1 = 0;
  { int idx = pos*16 + lane;      if (idx < hi*16) hp0 = hp[idx];
    idx = (pos+32)*16 + lane;     if (idx < hi*16) hp1 = hp[idx]; }
  if (lane < 8){
    int idx = pos*2 + lane;       if (idx < hi*2) sd0 = ((const int*)sdp)[idx];
    idx = (pos+32)*2 + lane;      if (idx < hi*2) sd1 = ((const int*)sdp)[idx];
  }
  for (; pos < hi; pos += 32){
    int np = pos + 64;
    u32 hp2 = 0; int sd2 = 0;
    { int idx = np*16 + lane; if (idx < hi*16) hp2 = hp[idx]; }
    if (lane < 8){ int idx = np*2 + lane; if (idx < hi*2) sd2 = ((const int*)sdp)[idx]; }
    hws[w][lane] = hp0;
    int sn = __shfl(sd0, 2*eg);
    int ds = __shfl(sd0, 2*eg + 1);
    bool valid = (pos + eg < hi);
    int sr = sn - n0; sr = sr < 0 ? 0 : (sr > 15 ? 15 : sr);
    const u32* Tr = Tt + sr*TT_ROW;
    const u32* T0 = Tr + 34*kk;
    const uint4* Hp4 = (const uint4*)&hws[w][eg*16];
    union{u32 u; h16x2 h;} b2u; b2u.u = Tr[544 + kk];
    float m0 = (float)b2u.h[0], m1 = (float)b2u.h[1];
    #pragma unroll
    for (int g = 0; g < 4; g++){
      uint4 hv4 = Hp4[g];
      m0 = dot2f(hv4.x, T0[4*g+0], m0);  m1 = dot2f(hv4.x, T0[17+4*g+0], m1);
      m0 = dot2f(hv4.y, T0[4*g+1], m0);  m1 = dot2f(hv4.y, T0[17+4*g+1], m1);
      m0 = dot2f(hv4.z, T0[4*g+2], m0);  m1 = dot2f(hv4.z, T0[17+4*g+2], m1);
      m0 = dot2f(hv4.w, T0[4*g+3], m0);  m1 = dot2f(hv4.w, T0[17+4*g+3], m1);
    }
    if (valid){
      msgp[(size_t)ds*16 + kk] = pkh2(m0, m1);   // f16-packed 64B row store
    }
    hp0 = hp1; sd0 = sd1; hp1 = hp2; sd1 = sd2;
  }
  #undef AFR
}

// ---------- fused: agg = mean(f16 msg rows); feat = relu(agg + froot); m = feat@w+b ----------
// optional: write clique part of the final output (outp != nullptr)
__global__ __launch_bounds__(256) void k_update_lin(const u32* __restrict__ msgp,
                           const int* __restrict__ doffs, const int* __restrict__ deg,
                           const float* __restrict__ feat_root, int M,
                           const void* __restrict__ w, long woff,
                           const void* __restrict__ b, long boff,
                           const int* __restrict__ flag,
                           float* __restrict__ feat, float* __restrict__ mout,
                           void* __restrict__ outp){
  __shared__ float wsm[1024], bs[32], rows[8][33];
  int tid = threadIdx.x;
  int f = *flag;
  for (int idx = tid; idx < 1024; idx += 256) wsm[idx] = ldw(w, woff + idx, f);
  if (tid < 32) bs[tid] = ldw(b, boff + tid, f);
  int nl = tid >> 5, o = tid & 31;
  int n = blockIdx.x*8 + nl;
  long i = (long)n*32 + o;
  if (n < M){
    int lo = doffs[n], dg = deg[n];
    float a = 0.f;
    for (int k = 0; k < dg; k++){
      union{u32 u; h16x2 h;} c;
      c.u = msgp[(size_t)(lo + k)*16 + (o >> 1)];
      a += (float)c.h[o & 1];
    }
    float d = (float)(dg > 1 ? dg : 1);
    float v = fmaxf(a/d + feat_root[i], 0.f);
    rows[nl][o] = v;
    feat[i] = v;
    if (outp){
      long oi = (long)Nn*32 + i;
      if (f) ((float*)outp)[oi] = v;
      else   ((u16*)outp)[oi]   = f2b(v);
    }
  }
  __syncthreads();
  if (n >= M) return;
  float acc = bs[o];
  #pragma unroll
  for (int j = 0; j < 32; j++) acc += rows[nl][j]*wsm[j*32+o];
  mout[i] = acc;
}

// ---------- final store: node part only (clique part folded into last update) ----------
__global__ __launch_bounds__(256) void k_store(const float* __restrict__ x,
                      const float* __restrict__ mC, const int* __restrict__ sidx,
                      const int* __restrict__ soffs, const int* __restrict__ sdeg,
                      void* __restrict__ out, const int* __restrict__ flag){
  int i = blockIdx.x*256 + threadIdx.x;
  if (i >= Nn*32) return;
  int n = i >> 5, o = i & 31;
  int lo = soffs[n], dg = sdeg[n];
  float a = 0.f;
  for (int k = 0; k < dg; k++) a += mC[(size_t)sidx[lo + k]*32 + o];
  float v = x[i] + a/(float)(dg > 1 ? dg : 1);
  if (*flag) ((float*)out)[i] = v;
  else       ((u16*)out)[i]   = f2b(v);
}

extern "C" void kernel_launch(void* const* d_in, const int* in_sizes, int n_in,
                              void* d_out, int out_size, void* d_ws, size_t ws_size,
                              hipStream_t stream){
  const int* ei  = (const int*)d_in[1];
  const int* n2c = (const int*)d_in[4];
  const int* cei = (const int*)d_in[5];
  const void *efr = d_in[2], *cefr = d_in[6];
  const void *nn1w = d_in[7], *nn1b = d_in[8], *nn2w = d_in[9], *nn2b = d_in[10],
             *rootw = d_in[11], *rootb = d_in[12], *n2cw = d_in[13], *n2cb = d_in[14],
             *cnn1w = d_in[15], *cnn1b = d_in[16], *cnn2w = d_in[17], *cnn2b = d_in[18],
             *crootw = d_in[19], *crootb = d_in[20], *c2nw = d_in[21], *c2nb = d_in[22];

  char* ws = (char*)d_ws;
  size_t off = 0;
  auto alloc = [&](size_t bytes){ void* p = ws + off; off += (bytes + 255) & ~(size_t)255; return p; };

  // ---- zeroed region (counters only; single small memset) ----
  size_t zstart = off;
  int* deg_nd  = (int*)alloc((size_t)Nn*4);
  int* deg_ce  = (int*)alloc((size_t)NCc*4);
  int* deg_n2c = (int*)alloc((size_t)NCc*4);
  int* deg_c2n = (int*)alloc((size_t)Nn*4);
  int* cnt_sn  = (int*)alloc((size_t)Nn*4);
  int* cnt_sc  = (int*)alloc((size_t)NCc*4);
  int* cur_n   = (int*)alloc((size_t)Nn*4);
  int* cur_c   = (int*)alloc((size_t)NCc*4);
  int* cur_an  = (int*)alloc((size_t)Nn*4);
  int* cur_ac  = (int*)alloc((size_t)NCc*4);
  int* cur_dn  = (int*)alloc((size_t)Nn*4);
  int* cur_dc  = (int*)alloc((size_t)NCc*4);
  u32* maxbits = (u32*)alloc(256);
  int* zcnt = (int*)((char*)maxbits + 4);
  int* flag = (int*)((char*)maxbits + 8);
  int* done = (int*)((char*)maxbits + 12);
  size_t zbytes = off - zstart;

  // ---- non-zeroed ----
  float* xB  = (float*)alloc((size_t)Nn*32*4);
  float* xC  = (float*)alloc((size_t)Nn*32*4);
  float* cC0 = (float*)alloc((size_t)NCc*32*4);
  float* cC1 = (float*)alloc((size_t)NCc*32*4);
  float* frn = (float*)alloc((size_t)Nn*32*4);
  float* frc = (float*)alloc((size_t)NCc*32*4);
  u32* msgN = (u32*)alloc((size_t)Ee*16*4);
  u32* msgC = (u32*)alloc((size_t)ECc*16*4);
  float* mN  = (float*)alloc((size_t)Nn*32*4);
  float* mC  = (float*)alloc((size_t)NCc*32*4);
  int* offs_n  = (int*)alloc((size_t)Nn*4);
  int* offs_c  = (int*)alloc((size_t)NCc*4);
  int* offs_an = (int*)alloc((size_t)Nn*4);
  int* offs_ac = (int*)alloc((size_t)NCc*4);
  int* doffs_n = (int*)alloc((size_t)Nn*4);
  int* doffs_c = (int*)alloc((size_t)NCc*4);
  int* an2c = (int*)alloc((size_t)Aa*4);
  int* ac2n = (int*)alloc((size_t)Aa*4);
  int2* sdp_n = (int2*)alloc((size_t)Ee*8);
  int2* sdp_c = (int2*)alloc((size_t)ECc*8);
  u16* Wp4 = (u16*)alloc((size_t)4*WPSZ*2);
  u32* hp_n = (u32*)alloc((size_t)2*Ee*16*4);
  u32* hp_c = (u32*)alloc((size_t)2*ECc*16*4);

  auto nb = [](int n){ return (n + 255)/256; };

  // 1. memset counters (~0.7 MB)
  hipMemsetAsync(ws + zstart, 0, zbytes, stream);
  // 2. dtype detect + all histograms
  k_detect_count<<<nb(2*Ee + 2*ECc + 2*Aa),256,0,stream>>>((const u16*)d_in[0], Nn*32,
      maxbits, zcnt, done, flag, ei, cei, n2c,
      deg_nd, deg_ce, deg_n2c, deg_c2n, cnt_sn, cnt_sc);
  // 3. single-pass 6-way scan
  k_scan1<<<NSEGB,256,0,stream>>>(cnt_sn, cnt_sc, deg_c2n, deg_n2c, deg_nd, deg_ce,
      offs_n, offs_c, offs_an, offs_ac, doffs_n, doffs_c);
  // 4. place + payload pack + assignment CSRs + weight pack
  k_place_pack<<<PB_EN+PB_EC+PB_AS+PB_WP,256,0,stream>>>(ei, cei, n2c, efr, cefr,
      nn1w, nn1b, cnn1w, cnn1b, nn2w, nn2b, rootw, cnn2w, cnn2b, crootw,
      offs_n, offs_c, offs_an, offs_ac, doffs_n, doffs_c,
      cur_n, cur_c, cur_an, cur_ac, cur_dn, cur_dc,
      sdp_n, sdp_c, hp_n, hp_c, an2c, ac2n, flag, Wp4);

  int Gn = (Nn + 15)/16, Gc = (NCc + 15)/16;

  // ---- layer 0 ----
  k_conv_fused<<<Gn,512,0,stream>>>(d_in[0], 1, nullptr, nullptr, nullptr, nullptr, Nn,
      sdp_n, hp_n, offs_n, Ee, Wp4 + 0*WPSZ, rootb, 0, flag, frn, msgN);
  k_update_lin<<<(Nn+7)/8,256,0,stream>>>(msgN, doffs_n, deg_nd, frn, Nn,
      n2cw, 0, n2cb, 0, flag, xB, mN, nullptr);
  k_conv_fused<<<Gc,512,0,stream>>>(d_in[3], 1, mN, an2c, offs_ac, deg_n2c, NCc,
      sdp_c, hp_c, offs_c, ECc, Wp4 + 1*WPSZ, crootb, 0, flag, frc, msgC);
  k_update_lin<<<(NCc+7)/8,256,0,stream>>>(msgC, doffs_c, deg_ce, frc, NCc,
      c2nw, 0, c2nb, 0, flag, cC0, mC, nullptr);
  // ---- layer 1 ----
  k_conv_fused<<<Gn,512,0,stream>>>(xB, 0, mC, ac2n, offs_an, deg_c2n, Nn,
      sdp_n, hp_n + (size_t)Ee*16, offs_n, Ee, Wp4 + 2*WPSZ, rootb, 32, flag, frn, msgN);
  k_update_lin<<<(Nn+7)/8,256,0,stream>>>(msgN, doffs_n, deg_nd, frn, Nn,
      n2cw, 1024, n2cb, 32, flag, xC, mN, nullptr);
  k_conv_fused<<<Gc,512,0,stream>>>(cC0, 0, mN, an2c, offs_ac, deg_n2c, NCc,
      sdp_c, hp_c + (size_t)ECc*16, offs_c, ECc, Wp4 + 3*WPSZ, crootb, 32, flag, frc, msgC);
  k_update_lin<<<(NCc+7)/8,256,0,stream>>>(msgC, doffs_c, deg_ce, frc, NCc,
      c2nw, 1024, c2nb, 32, flag, cC1, mC, d_out);   // clique output folded here
  // ---- output (node part only) ----
  k_store<<<nb(Nn*32),256,0,stream>>>(xC, mC, ac2n, offs_an, deg_c2n, d_out, flag);
}

// Round 8
// 291.582 us; speedup vs baseline: 2.5451x; 1.0007x over previous
//
#include <hip/hip_runtime.h>
#include <hip/hip_bf16.h>

typedef unsigned int u32;
typedef unsigned short u16;

#define DEVINL __device__ __forceinline__

constexpr int Nn  = 25000;
constexpr int Ee  = 100000;
constexpr int NCc = 8000;
constexpr int Aa  = 50000;
constexpr int ECc = 24000;
constexpr int TCOLS = 1088;     // 34 k-rows * 32 o-cols
constexpr int WPSZ  = TCOLS*32; // one packed weight set
constexpr int TT_ROW = 561;     // u32 per T row
constexpr int NB_N = (Nn + 255)/256;   // 98
constexpr int NB_C = (NCc + 255)/256;  // 32
constexpr int NSEGB = 3*(NB_N + NB_C); // 390
// k_place_pack block ranges
constexpr int PB_EN = (Ee + 255)/256;
constexpr int PB_EC = (ECc + 255)/256;
constexpr int PB_AS = (2*Aa + 255)/256;
constexpr int PB_WP = (4*WPSZ + 255)/256;

typedef float f32x4 __attribute__((ext_vector_type(4)));
typedef _Float16 h16x2 __attribute__((ext_vector_type(2)));
typedef _Float16 h16x8 __attribute__((ext_vector_type(8)));

DEVINL float b2f(u16 u){ union{u32 i;float f;}v; v.i = ((u32)u)<<16; return v.f; }
DEVINL float bfl(u32 u){ union{u32 i;float f;}v; v.i = u<<16; return v.f; }
DEVINL float bfh(u32 u){ union{u32 i;float f;}v; v.i = u & 0xffff0000u; return v.f; }
DEVINL u16 f2b(float f){ union{float f;u32 i;}v; v.f=f; u32 i=v.i;
  return (u16)((i + 0x7fffu + ((i>>16)&1u)) >> 16); }
DEVINL u16 f2h(float x){ union{ _Float16 h; u16 u; } v; v.h = (_Float16)x; return v.u; }
DEVINL u32 pkh2(float a, float b){
  union{ _Float16 h[2]; u32 u; } v;
  v.h[0] = (_Float16)a; v.h[1] = (_Float16)b; return v.u;
}
DEVINL float ldw(const void* p, long i, int f){
  return f ? ((const float*)p)[i] : b2f(((const u16*)p)[i]);
}
DEVINL float dot2f(u32 a, u32 b, float c){
  union U{u32 u; h16x2 h;};
  U ua; ua.u = a; U ub; ub.u = b;
#if __has_builtin(__builtin_amdgcn_fdot2)
  return __builtin_amdgcn_fdot2(ua.h, ub.h, c, false);
#else
  return c + (float)ua.h[0]*(float)ub.h[0] + (float)ua.h[1]*(float)ub.h[1];
#endif
}

// ---------- fused: all histograms (full grid) + dtype detect (first 256 blocks, uint4-vectorized) ----------
__global__ __launch_bounds__(256) void k_detect_count(const u16* __restrict__ p, int n,
                        u32* __restrict__ maxbits, int* __restrict__ zcnt,
                        int* __restrict__ done, int* __restrict__ flag,
                        const int* __restrict__ ei, const int* __restrict__ cei,
                        const int* __restrict__ n2c,
                        int* __restrict__ deg_nd, int* __restrict__ deg_ce,
                        int* __restrict__ deg_n2c, int* __restrict__ deg_c2n,
                        int* __restrict__ cnt_sn, int* __restrict__ cnt_sc){
  int i0 = blockIdx.x*256 + threadIdx.x;
  { int t = i0;
    if (t < Ee)                             atomicAdd(&deg_nd[ei[Ee + t]], 1);
    else if ((t -= Ee) < ECc)               atomicAdd(&deg_ce[cei[ECc + t]], 1);
    else if ((t -= ECc) < Aa)               atomicAdd(&deg_n2c[n2c[Aa + t]], 1);
    else if ((t -= Aa) < Aa)                atomicAdd(&deg_c2n[n2c[t]], 1);
    else if ((t -= Aa) < Ee)                atomicAdd(&cnt_sn[ei[t]], 1);
    else if ((t -= Ee) < ECc)               atomicAdd(&cnt_sc[cei[t]], 1);
  }
  if (blockIdx.x >= 256) return;
  float lm = 0.f; int lz = 0;
  const uint4* pv = (const uint4*)p;   // 8 u16 per load
  int nv = n >> 3;
  for (int i = i0; i < nv; i += 256*256){
    uint4 q = pv[i];
    u32 wv[4] = {q.x, q.y, q.z, q.w};
    #pragma unroll
    for (int j = 0; j < 4; j++){
      u32 x = wv[j];
      if ((x & 0xffffu) == 0) lz++;
      if ((x >> 16) == 0) lz++;
      lm = fmaxf(lm, fabsf(bfl(x)));
      lm = fmaxf(lm, fabsf(bfh(x)));
    }
  }
  #pragma unroll
  for (int off = 32; off; off >>= 1){
    lm = fmaxf(lm, __shfl_down(lm, off));
    lz += __shfl_down(lz, off);
  }
  __shared__ float smax[4]; __shared__ int szc[4];
  if ((threadIdx.x & 63) == 0){
    smax[threadIdx.x >> 6] = lm;
    szc[threadIdx.x >> 6] = lz;
  }
  __syncthreads();
  if (threadIdx.x == 0){
    float m = fmaxf(fmaxf(smax[0], smax[1]), fmaxf(smax[2], smax[3]));
    int z = szc[0] + szc[1] + szc[2] + szc[3];
    atomicMax(maxbits, __float_as_uint(m));
    atomicAdd(zcnt, z);
    __threadfence();
    if (atomicAdd(done, 1) == 255){
      float mm = __uint_as_float(*maxbits);
      *flag = (mm > 1e6f || *zcnt > n/4) ? 1 : 0;
    }
  }
}

// ---------- single-pass 6-segment scan ----------
DEVINL void segof(int bid, int& seg, int& rb){
  seg = 0; rb = bid;
  while (true){
    int nb = (seg & 1) ? NB_C : NB_N;
    if (rb < nb) break;
    rb -= nb; seg++;
  }
}

__global__ __launch_bounds__(256) void k_scan1(
    const int* __restrict__ c0, const int* __restrict__ c1,
    const int* __restrict__ c2, const int* __restrict__ c3,
    const int* __restrict__ c4, const int* __restrict__ c5,
    int* __restrict__ o0, int* __restrict__ o1, int* __restrict__ o2,
    int* __restrict__ o3, int* __restrict__ o4, int* __restrict__ o5){
  __shared__ int s[256];
  __shared__ int red[256];
  int seg, rb; segof(blockIdx.x, seg, rb);
  const int* cnt; int* offs;
  switch (seg){
    case 0: cnt=c0; offs=o0; break;
    case 1: cnt=c1; offs=o1; break;
    case 2: cnt=c2; offs=o2; break;
    case 3: cnt=c3; offs=o3; break;
    case 4: cnt=c4; offs=o4; break;
    default: cnt=c5; offs=o5; break;
  }
  int M = (seg & 1) ? NCc : Nn;
  int t = threadIdx.x;
  int part = 0;
  for (int j = t; j < rb*256; j += 256) part += cnt[j];
  red[t] = part; __syncthreads();
  #pragma unroll
  for (int d = 128; d; d >>= 1){
    if (t < d) red[t] += red[t + d];
    __syncthreads();
  }
  int prefix = red[0];
  int i = rb*256 + t;
  int v = (i < M) ? cnt[i] : 0;
  s[t] = v; __syncthreads();
  for (int d = 1; d < 256; d <<= 1){
    int tv = (t >= d) ? s[t-d] : 0;
    __syncthreads();
    s[t] += tv;
    __syncthreads();
  }
  if (i < M) offs[i] = prefix + s[t] - v;
}

// ---------- fused: place (src+dst slots) + payload pack (128B/edge hp rows) + weight pack ----------
__global__ __launch_bounds__(256) void k_place_pack(
    const int* __restrict__ ei, const int* __restrict__ cei, const int* __restrict__ n2c,
    const void* __restrict__ ef, const void* __restrict__ cef,
    const void* __restrict__ nn1w, const void* __restrict__ nn1b,
    const void* __restrict__ cnn1w, const void* __restrict__ cnn1b,
    const void* __restrict__ nn2w, const void* __restrict__ nn2b, const void* __restrict__ rootw,
    const void* __restrict__ cnn2w, const void* __restrict__ cnn2b, const void* __restrict__ crootw,
    const int* __restrict__ offs_n, const int* __restrict__ offs_c,
    const int* __restrict__ offs_an, const int* __restrict__ offs_ac,
    const int* __restrict__ doffs_n, const int* __restrict__ doffs_c,
    int* __restrict__ cur_n, int* __restrict__ cur_c,
    int* __restrict__ cur_an, int* __restrict__ cur_ac,
    int* __restrict__ cur_dn, int* __restrict__ cur_dc,
    int2* __restrict__ sdp_n, int2* __restrict__ sdp_c,
    u32* __restrict__ hp_n, u32* __restrict__ hp_c,
    int* __restrict__ an2c, int* __restrict__ ac2n,
    const int* __restrict__ flag, u16* __restrict__ Wp4){
  int b = blockIdx.x, tid = threadIdx.x;
  int f = *flag;
  if (b < PB_EN + PB_EC){
    __shared__ float w1s[2][256], b1s[2][32];
    int isC = (b >= PB_EN);
    int e = (isC ? b - PB_EN : b)*256 + tid;
    int E = isC ? ECc : Ee;
    const void* W1 = isC ? cnn1w : nn1w;
    const void* B1 = isC ? cnn1b : nn1b;
    w1s[0][tid] = ldw(W1, tid, f);
    w1s[1][tid] = ldw(W1, 256 + tid, f);
    if (tid < 32){ b1s[0][tid] = ldw(B1, tid, f); b1s[1][tid] = ldw(B1, 32 + tid, f); }
    __syncthreads();
    if (e < E){
      const int* EI = isC ? cei : ei;
      int s = EI[e], d = EI[E + e];
      int* cur = isC ? cur_c : cur_n;
      const int* offs = isC ? offs_c : offs_n;
      int p = offs[s] + atomicAdd(&cur[s], 1);
      const int* dofs = isC ? doffs_c : doffs_n;
      int* curd = isC ? cur_dc : cur_dn;
      int dsl = dofs[d] + atomicAdd(&curd[d], 1);
      (isC ? sdp_c : sdp_n)[p] = make_int2(s, dsl);
      const void* EF = isC ? cef : ef;
      float ev[8];
      #pragma unroll
      for (int j = 0; j < 8; j++) ev[j] = ldw(EF, (long)e*8 + j, f);
      // one 128B row per edge: [layer0: 16 u32][layer1: 16 u32]
      u32* hq = (isC ? hp_c : hp_n) + (size_t)p*32;
      #pragma unroll
      for (int l = 0; l < 2; l++){
        #pragma unroll
        for (int kk = 0; kk < 16; kk++){
          float a0 = b1s[l][2*kk], a1 = b1s[l][2*kk+1];
          #pragma unroll
          for (int j = 0; j < 8; j++){
            a0 += ev[j]*w1s[l][j*32 + 2*kk];
            a1 += ev[j]*w1s[l][j*32 + 2*kk + 1];
          }
          hq[l*16 + kk] = pkh2(fmaxf(a0, 0.f), fmaxf(a1, 0.f));
        }
      }
    }
  } else if (b < PB_EN + PB_EC + PB_AS){
    int i = (b - PB_EN - PB_EC)*256 + tid;
    if (i < Aa){
      int c = n2c[Aa + i];
      an2c[offs_ac[c] + atomicAdd(&cur_ac[c], 1)] = n2c[i];
    } else if ((i -= Aa) < Aa){
      int nd = n2c[i];
      ac2n[offs_an[nd] + atomicAdd(&cur_an[nd], 1)] = n2c[Aa + i];
    }
  } else {
    int i = (b - PB_EN - PB_EC - PB_AS)*256 + tid;
    if (i >= 4*WPSZ) return;
    int set = i / WPSZ, j = i - set*WPSZ;
    int l = set >> 1, isC = set & 1;
    const void* W2 = isC ? cnn2w : nn2w;
    const void* B2 = isC ? cnn2b : nn2b;
    const void* RW = isC ? crootw : rootw;
    int col = j >> 5, ii = j & 31;
    float v;
    if (col < 1024)      v = ldw(W2, (long)l*32768 + ((col>>5)<<10) + (ii<<5) + (col&31), f);
    else if (col < 1056) v = ldw(B2, (long)l*1024 + (ii<<5) + (col-1024), f);
    else                 v = ldw(RW, (long)l*1024 + (ii<<5) + (col-1056), f);
    Wp4[i] = f2h(v);
  }
}

// ---------- fused conv: f16 MFMA T + dot2 streaming edges; f16-packed msg slot-store ----------
// hp points at layer base (row stride 32 u32: both layers share the edge's 128B row)
__global__ __launch_bounds__(512) void k_conv_fused(const void* __restrict__ base, int braw,
                           const float* __restrict__ adm, const int* __restrict__ sidx,
                           const int* __restrict__ soffs, const int* __restrict__ sdeg, int M,
                           const int2* __restrict__ sdp, const u32* __restrict__ hp,
                           const int* __restrict__ offs, int E_,
                           const u16* __restrict__ Wp,
                           const void* __restrict__ rb, long rboff,
                           const int* __restrict__ flag,
                           float* __restrict__ feat_root, u32* __restrict__ msgp){
  __shared__ __align__(16) u32 Tt[16*TT_ROW];
  __shared__ __align__(16) u32 hws[8][64];
  int tid = threadIdx.x;
  int w = tid >> 6, lane = tid & 63;
  int quad = lane >> 4, lm = lane & 15;
  int n0 = blockIdx.x * 16;
  int f = *flag;
  int n = n0 + lm;
  int nc = n < M ? n : M-1;
  long bidx = (long)nc*32 + quad*8;
  float fv[8];
  if (braw && f == 0){
    uint4 q = *(const uint4*)((const u16*)base + bidx);
    fv[0]=bfl(q.x); fv[1]=bfh(q.x); fv[2]=bfl(q.y); fv[3]=bfh(q.y);
    fv[4]=bfl(q.z); fv[5]=bfh(q.z); fv[6]=bfl(q.w); fv[7]=bfh(q.w);
  } else {
    const float4* bp = (const float4*)((const float*)base + bidx);
    float4 q0 = bp[0], q1 = bp[1];
    fv[0]=q0.x; fv[1]=q0.y; fv[2]=q0.z; fv[3]=q0.w;
    fv[4]=q1.x; fv[5]=q1.y; fv[6]=q1.z; fv[7]=q1.w;
  }
  if (adm){
    int slo = soffs[nc], scnt = sdeg[nc];
    float ac[8] = {0,0,0,0,0,0,0,0};
    for (int k = 0; k < scnt; k++){
      const float4* mp = (const float4*)(adm + (size_t)sidx[slo + k]*32 + quad*8);
      float4 a0 = mp[0], a1 = mp[1];
      ac[0]+=a0.x; ac[1]+=a0.y; ac[2]+=a0.z; ac[3]+=a0.w;
      ac[4]+=a1.x; ac[5]+=a1.y; ac[6]+=a1.z; ac[7]+=a1.w;
    }
    float inv = 1.f/(float)(scnt > 1 ? scnt : 1);
    #pragma unroll
    for (int j = 0; j < 8; j++) fv[j] += ac[j]*inv;
  }
  union { h16x8 v; u32 u[4]; } bf;
  #pragma unroll
  for (int j = 0; j < 4; j++) bf.u[j] = pkh2(fv[2*j], fv[2*j+1]);

  #define AFR(ct) (*(const h16x8*)(Wp + (size_t)((ct)*16 + lm)*32 + quad*8))
  f32x4 z4 = {0.f, 0.f, 0.f, 0.f};
  #pragma unroll
  for (int g = 0; g < 2; g++){
    int q = w + 8*g;
    f32x4 c0 = __builtin_amdgcn_mfma_f32_16x16x32_f16(AFR(4*q+0), bf.v, z4, 0, 0, 0);
    f32x4 c1 = __builtin_amdgcn_mfma_f32_16x16x32_f16(AFR(4*q+1), bf.v, z4, 0, 0, 0);
    f32x4 c2 = __builtin_amdgcn_mfma_f32_16x16x32_f16(AFR(4*q+2), bf.v, z4, 0, 0, 0);
    f32x4 c3 = __builtin_amdgcn_mfma_f32_16x16x32_f16(AFR(4*q+3), bf.v, z4, 0, 0, 0);
    int rbase = lm*TT_ROW;
    int ob = quad*4;
    #pragma unroll
    for (int i = 0; i < 4; i++){
      Tt[rbase + (ob+i)*17 + q]      = pkh2(c0[i], c2[i]);
      Tt[rbase + (16+ob+i)*17 + q]   = pkh2(c1[i], c3[i]);
    }
  }
  if (w < 4){
    int ct = 64 + w;
    f32x4 c = __builtin_amdgcn_mfma_f32_16x16x32_f16(AFR(ct), bf.v, z4, 0, 0, 0);
    if (ct < 66){
      int p0 = (ct-64)*8 + quad*2;
      Tt[lm*TT_ROW + 544 + p0]     = pkh2(c[0], c[1]);
      Tt[lm*TT_ROW + 544 + p0 + 1] = pkh2(c[2], c[3]);
    } else if (n < M){
      int o = (ct-66)*16 + quad*4;
      float4 v = make_float4(c[0] + ldw(rb, rboff+o,   f),
                             c[1] + ldw(rb, rboff+o+1, f),
                             c[2] + ldw(rb, rboff+o+2, f),
                             c[3] + ldw(rb, rboff+o+3, f));
      *(float4*)&feat_root[(size_t)n*32 + o] = v;
    }
  }
  __syncthreads();

  int lo = offs[n0];
  int hi = (n0 + 16 < M) ? offs[n0 + 16] : E_;
  int eg = quad, kk = lm;
  int le = lane >> 4, wk = lane & 15;   // lane's (edge-in-group, word)
  int pos = lo + w*4;
  u32 hp0 = 0, hp1 = 0; int sd0 = 0, sd1 = 0;
  { int ep = pos + le;
    if (ep < hi)      hp0 = hp[(size_t)ep*32 + wk];
    if (ep + 32 < hi) hp1 = hp[(size_t)(ep + 32)*32 + wk]; }
  if (lane < 8){
    int idx = pos*2 + lane;       if (idx < hi*2) sd0 = ((const int*)sdp)[idx];
    idx = (pos+32)*2 + lane;      if (idx < hi*2) sd1 = ((const int*)sdp)[idx];
  }
  for (; pos < hi; pos += 32){
    int np = pos + 64;
    u32 hp2 = 0; int sd2 = 0;
    { int ep = np + le; if (ep < hi) hp2 = hp[(size_t)ep*32 + wk]; }
    if (lane < 8){ int idx = np*2 + lane; if (idx < hi*2) sd2 = ((const int*)sdp)[idx]; }
    hws[w][lane] = hp0;
    int sn = __shfl(sd0, 2*eg);
    int ds = __shfl(sd0, 2*eg + 1);
    bool valid = (pos + eg < hi);
    int sr = sn - n0; sr = sr < 0 ? 0 : (sr > 15 ? 15 : sr);
    const u32* Tr = Tt + sr*TT_ROW;
    const u32* T0 = Tr + 34*kk;
    const uint4* Hp4 = (const uint4*)&hws[w][eg*16];
    union{u32 u; h16x2 h;} b2u; b2u.u = Tr[544 + kk];
    float m0 = (float)b2u.h[0], m1 = (float)b2u.h[1];
    #pragma unroll
    for (int g = 0; g < 4; g++){
      uint4 hv4 = Hp4[g];
      m0 = dot2f(hv4.x, T0[4*g+0], m0);  m1 = dot2f(hv4.x, T0[17+4*g+0], m1);
      m0 = dot2f(hv4.y, T0[4*g+1], m0);  m1 = dot2f(hv4.y, T0[17+4*g+1], m1);
      m0 = dot2f(hv4.z, T0[4*g+2], m0);  m1 = dot2f(hv4.z, T0[17+4*g+2], m1);
      m0 = dot2f(hv4.w, T0[4*g+3], m0);  m1 = dot2f(hv4.w, T0[17+4*g+3], m1);
    }
    if (valid){
      msgp[(size_t)ds*16 + kk] = pkh2(m0, m1);   // f16-packed 64B row store
    }
    hp0 = hp1; sd0 = sd1; hp1 = hp2; sd1 = sd2;
  }
  #undef AFR
}

// ---------- fused: agg = mean(f16 msg rows); feat = relu(agg + froot); m = feat@w+b ----------
__global__ __launch_bounds__(256) void k_update_lin(const u32* __restrict__ msgp,
                           const int* __restrict__ doffs, const int* __restrict__ deg,
                           const float* __restrict__ feat_root, int M,
                           const void* __restrict__ w, long woff,
                           const void* __restrict__ b, long boff,
                           const int* __restrict__ flag,
                           float* __restrict__ feat, float* __restrict__ mout,
                           void* __restrict__ outp){
  __shared__ float wsm[1024], bs[32], rows[8][33];
  int tid = threadIdx.x;
  int f = *flag;
  for (int idx = tid; idx < 1024; idx += 256) wsm[idx] = ldw(w, woff + idx, f);
  if (tid < 32) bs[tid] = ldw(b, boff + tid, f);
  int nl = tid >> 5, o = tid & 31;
  int n = blockIdx.x*8 + nl;
  long i = (long)n*32 + o;
  if (n < M){
    int lo = doffs[n], dg = deg[n];
    float a = 0.f;
    for (int k = 0; k < dg; k++){
      union{u32 u; h16x2 h;} c;
      c.u = msgp[(size_t)(lo + k)*16 + (o >> 1)];
      a += (float)c.h[o & 1];
    }
    float d = (float)(dg > 1 ? dg : 1);
    float v = fmaxf(a/d + feat_root[i], 0.f);
    rows[nl][o] = v;
    feat[i] = v;
    if (outp){
      long oi = (long)Nn*32 + i;
      if (f) ((float*)outp)[oi] = v;
      else   ((u16*)outp)[oi]   = f2b(v);
    }
  }
  __syncthreads();
  if (n >= M) return;
  float acc = bs[o];
  #pragma unroll
  for (int j = 0; j < 32; j++) acc += rows[nl][j]*wsm[j*32+o];
  mout[i] = acc;
}

// ---------- final store: node part only ----------
__global__ __launch_bounds__(256) void k_store(const float* __restrict__ x,
                      const float* __restrict__ mC, const int* __restrict__ sidx,
                      const int* __restrict__ soffs, const int* __restrict__ sdeg,
                      void* __restrict__ out, const int* __restrict__ flag){
  int i = blockIdx.x*256 + threadIdx.x;
  if (i >= Nn*32) return;
  int n = i >> 5, o = i & 31;
  int lo = soffs[n], dg = sdeg[n];
  float a = 0.f;
  for (int k = 0; k < dg; k++) a += mC[(size_t)sidx[lo + k]*32 + o];
  float v = x[i] + a/(float)(dg > 1 ? dg : 1);
  if (*flag) ((float*)out)[i] = v;
  else       ((u16*)out)[i]   = f2b(v);
}

extern "C" void kernel_launch(void* const* d_in, const int* in_sizes, int n_in,
                              void* d_out, int out_size, void* d_ws, size_t ws_size,
                              hipStream_t stream){
  const int* ei  = (const int*)d_in[1];
  const int* n2c = (const int*)d_in[4];
  const int* cei = (const int*)d_in[5];
  const void *efr = d_in[2], *cefr = d_in[6];
  const void *nn1w = d_in[7], *nn1b = d_in[8], *nn2w = d_in[9], *nn2b = d_in[10],
             *rootw = d_in[11], *rootb = d_in[12], *n2cw = d_in[13], *n2cb = d_in[14],
             *cnn1w = d_in[15], *cnn1b = d_in[16], *cnn2w = d_in[17], *cnn2b = d_in[18],
             *crootw = d_in[19], *crootb = d_in[20], *c2nw = d_in[21], *c2nb = d_in[22];

  char* ws = (char*)d_ws;
  size_t off = 0;
  auto alloc = [&](size_t bytes){ void* p = ws + off; off += (bytes + 255) & ~(size_t)255; return p; };

  // ---- zeroed region ----
  size_t zstart = off;
  int* deg_nd  = (int*)alloc((size_t)Nn*4);
  int* deg_ce  = (int*)alloc((size_t)NCc*4);
  int* deg_n2c = (int*)alloc((size_t)NCc*4);
  int* deg_c2n = (int*)alloc((size_t)Nn*4);
  int* cnt_sn  = (int*)alloc((size_t)Nn*4);
  int* cnt_sc  = (int*)alloc((size_t)NCc*4);
  int* cur_n   = (int*)alloc((size_t)Nn*4);
  int* cur_c   = (int*)alloc((size_t)NCc*4);
  int* cur_an  = (int*)alloc((size_t)Nn*4);
  int* cur_ac  = (int*)alloc((size_t)NCc*4);
  int* cur_dn  = (int*)alloc((size_t)Nn*4);
  int* cur_dc  = (int*)alloc((size_t)NCc*4);
  u32* maxbits = (u32*)alloc(256);
  int* zcnt = (int*)((char*)maxbits + 4);
  int* flag = (int*)((char*)maxbits + 8);
  int* done = (int*)((char*)maxbits + 12);
  size_t zbytes = off - zstart;

  // ---- non-zeroed ----
  float* xB  = (float*)alloc((size_t)Nn*32*4);
  float* xC  = (float*)alloc((size_t)Nn*32*4);
  float* cC0 = (float*)alloc((size_t)NCc*32*4);
  float* cC1 = (float*)alloc((size_t)NCc*32*4);
  float* frn = (float*)alloc((size_t)Nn*32*4);
  float* frc = (float*)alloc((size_t)NCc*32*4);
  u32* msgN = (u32*)alloc((size_t)Ee*16*4);
  u32* msgC = (u32*)alloc((size_t)ECc*16*4);
  float* mN  = (float*)alloc((size_t)Nn*32*4);
  float* mC  = (float*)alloc((size_t)NCc*32*4);
  int* offs_n  = (int*)alloc((size_t)Nn*4);
  int* offs_c  = (int*)alloc((size_t)NCc*4);
  int* offs_an = (int*)alloc((size_t)Nn*4);
  int* offs_ac = (int*)alloc((size_t)NCc*4);
  int* doffs_n = (int*)alloc((size_t)Nn*4);
  int* doffs_c = (int*)alloc((size_t)NCc*4);
  int* an2c = (int*)alloc((size_t)Aa*4);
  int* ac2n = (int*)alloc((size_t)Aa*4);
  int2* sdp_n = (int2*)alloc((size_t)Ee*8);
  int2* sdp_c = (int2*)alloc((size_t)ECc*8);
  u16* Wp4 = (u16*)alloc((size_t)4*WPSZ*2);
  u32* hp_n = (u32*)alloc((size_t)Ee*32*4);    // 128B/edge, both layers
  u32* hp_c = (u32*)alloc((size_t)ECc*32*4);

  auto nb = [](int n){ return (n + 255)/256; };

  // 1. memset counters (~0.7 MB)
  hipMemsetAsync(ws + zstart, 0, zbytes, stream);
  // 2. dtype detect + all histograms
  k_detect_count<<<nb(2*Ee + 2*ECc + 2*Aa),256,0,stream>>>((const u16*)d_in[0], Nn*32,
      maxbits, zcnt, done, flag, ei, cei, n2c,
      deg_nd, deg_ce, deg_n2c, deg_c2n, cnt_sn, cnt_sc);
  // 3. single-pass 6-way scan
  k_scan1<<<NSEGB,256,0,stream>>>(cnt_sn, cnt_sc, deg_c2n, deg_n2c, deg_nd, deg_ce,
      offs_n, offs_c, offs_an, offs_ac, doffs_n, doffs_c);
  // 4. place + payload pack + assignment CSRs + weight pack
  k_place_pack<<<PB_EN+PB_EC+PB_AS+PB_WP,256,0,stream>>>(ei, cei, n2c, efr, cefr,
      nn1w, nn1b, cnn1w, cnn1b, nn2w, nn2b, rootw, cnn2w, cnn2b, crootw,
      offs_n, offs_c, offs_an, offs_ac, doffs_n, doffs_c,
      cur_n, cur_c, cur_an, cur_ac, cur_dn, cur_dc,
      sdp_n, sdp_c, hp_n, hp_c, an2c, ac2n, flag, Wp4);

  int Gn = (Nn + 15)/16, Gc = (NCc + 15)/16;

  // ---- layer 0 ----
  k_conv_fused<<<Gn,512,0,stream>>>(d_in[0], 1, nullptr, nullptr, nullptr, nullptr, Nn,
      sdp_n, hp_n, offs_n, Ee, Wp4 + 0*WPSZ, rootb, 0, flag, frn, msgN);
  k_update_lin<<<(Nn+7)/8,256,0,stream>>>(msgN, doffs_n, deg_nd, frn, Nn,
      n2cw, 0, n2cb, 0, flag, xB, mN, nullptr);
  k_conv_fused<<<Gc,512,0,stream>>>(d_in[3], 1, mN, an2c, offs_ac, deg_n2c, NCc,
      sdp_c, hp_c, offs_c, ECc, Wp4 + 1*WPSZ, crootb, 0, flag, frc, msgC);
  k_update_lin<<<(NCc+7)/8,256,0,stream>>>(msgC, doffs_c, deg_ce, frc, NCc,
      c2nw, 0, c2nb, 0, flag, cC0, mC, nullptr);
  // ---- layer 1 ----
  k_conv_fused<<<Gn,512,0,stream>>>(xB, 0, mC, ac2n, offs_an, deg_c2n, Nn,
      sdp_n, hp_n + 16, offs_n, Ee, Wp4 + 2*WPSZ, rootb, 32, flag, frn, msgN);
  k_update_lin<<<(Nn+7)/8,256,0,stream>>>(msgN, doffs_n, deg_nd, frn, Nn,
      n2cw, 1024, n2cb, 32, flag, xC, mN, nullptr);
  k_conv_fused<<<Gc,512,0,stream>>>(cC0, 0, mN, an2c, offs_ac, deg_n2c, NCc,
      sdp_c, hp_c + 16, offs_c, ECc, Wp4 + 3*WPSZ, crootb, 32, flag, frc, msgC);
  k_update_lin<<<(NCc+7)/8,256,0,stream>>>(msgC, doffs_c, deg_ce, frc, NCc,
      c2nw, 1024, c2nb, 32, flag, cC1, mC, d_out);
  // ---- output (node part only) ----
  k_store<<<nb(Nn*32),256,0,stream>>>(xC, mC, ac2n, offs_an, deg_c2n, d_out, flag);
}